// Round 3
// baseline (50.223 us; speedup 1.0000x reference)
//
#include <hip/hip_runtime.h>

// RoPE: out[..., 2i]   =  x[2i]*cos(ang_i) + x[2i+1]*sin(ang_i)
//       out[..., 2i+1] = -x[2i]*sin(ang_i) + x[2i+1]*cos(ang_i)
// ang_i = (clip(pos,0,8191)+1) * 10000^(-2*(i//2)/1024),  i in [0,512)
// 4 consecutive floats (indices 4t..4t+3) share theta index t = i//2.
// Streaming op: non-temporal load/store to avoid L2/LLC pollution.
// NOTE: nontemporal builtins need a NATIVE vector type, not HIP_vector_type.

typedef float v4f __attribute__((ext_vector_type(4)));

#define ROPE_NEG_LOG2_BASE_OVER_512 (-0.025952562069432518f) // -log2(10000)/512

__global__ __launch_bounds__(256) void RotaryPositionalEncoding_56178172231979_kernel(
    const float* __restrict__ x,
    const int*   __restrict__ positions,
    float*       __restrict__ out,
    int n4)                       // number of float4 elements
{
    const int stride = gridDim.x * blockDim.x;
    for (int idx = blockIdx.x * blockDim.x + threadIdx.x; idx < n4; idx += stride) {
        const int row = idx >> 8;   // 1024 floats/row = 256 float4/row
        const int t   = idx & 255;  // theta index = i//2 for this float4

        int p = positions[row];     // same addr across row's lanes -> L1 broadcast
        p = min(max(p, 0), 8191);
        const float m = (float)(p + 1);

        const float theta = exp2f(ROPE_NEG_LOG2_BASE_OVER_512 * (float)t);
        const float ang = m * theta;
        float s, c;
        __sincosf(ang, &s, &c);

        const v4f v = __builtin_nontemporal_load(reinterpret_cast<const v4f*>(x) + idx);
        v4f o;
        o.x =  v.x * c + v.y * s;
        o.y = -v.x * s + v.y * c;
        o.z =  v.z * c + v.w * s;
        o.w = -v.z * s + v.w * c;
        __builtin_nontemporal_store(o, reinterpret_cast<v4f*>(out) + idx);
    }
}

extern "C" void kernel_launch(void* const* d_in, const int* in_sizes, int n_in,
                              void* d_out, int out_size, void* d_ws, size_t ws_size,
                              hipStream_t stream) {
    const float* x         = (const float*)d_in[0];
    const int*   positions = (const int*)d_in[1];
    float*       out       = (float*)d_out;

    const int n4 = out_size / 4;   // 4*8192*1024/4 = 8388608
    const int block = 256;
    const int grid  = 2048;        // memory-bound: ~8 blocks/CU, grid-stride the rest

    RotaryPositionalEncoding_56178172231979_kernel<<<grid, block, 0, stream>>>(
        x, positions, out, n4);
}

// Round 4
// 46.392 us; speedup vs baseline: 1.0826x; 1.0826x over previous
//
#include <hip/hip_runtime.h>

// RoPE: out[..., 2i]   =  x[2i]*cos(ang_i) + x[2i+1]*sin(ang_i)
//       out[..., 2i+1] = -x[2i]*sin(ang_i) + x[2i+1]*cos(ang_i)
// ang_i = (clip(pos,0,8191)+1) * 10000^(-2*(i//2)/1024),  i in [0,512)
// 4 consecutive floats (indices 4t..4t+3) share theta index t = i//2.
//
// R3 lesson: __builtin_nontemporal_* REGRESSED (46.6 -> 50.2 us) — default
// cached path wins for streaming mixed traffic on gfx950. Reverted.
// This round: compile-time trip count (16 float4/thread) + full unroll to
// deepen memory-level parallelism (many loads in flight per wave).

typedef float v4f __attribute__((ext_vector_type(4)));

#define ROPE_NEG_LOG2_BASE_OVER_512 (-0.025952562069432518f) // -log2(10000)/512
#define PER_THREAD 16

__global__ __launch_bounds__(256) void RotaryPositionalEncoding_56178172231979_kernel(
    const float* __restrict__ x,
    const int*   __restrict__ positions,
    float*       __restrict__ out)
{
    const int stride = gridDim.x * blockDim.x;           // in float4 units
    const int base   = blockIdx.x * blockDim.x + threadIdx.x;

    #pragma unroll
    for (int j = 0; j < PER_THREAD; ++j) {
        const int idx = base + j * stride;
        const int row = idx >> 8;   // 1024 floats/row = 256 float4/row
        const int t   = idx & 255;  // theta index = i//2 for this float4

        int p = positions[row];     // 128KB array, L2-resident broadcast
        p = min(max(p, 0), 8191);
        const float m = (float)(p + 1);

        const float theta = exp2f(ROPE_NEG_LOG2_BASE_OVER_512 * (float)t);
        const float ang = m * theta;
        float s, c;
        __sincosf(ang, &s, &c);

        const v4f v = reinterpret_cast<const v4f*>(x)[idx];
        v4f o;
        o.x =  v.x * c + v.y * s;
        o.y = -v.x * s + v.y * c;
        o.z =  v.z * c + v.w * s;
        o.w = -v.z * s + v.w * c;
        reinterpret_cast<v4f*>(out)[idx] = o;
    }
}

extern "C" void kernel_launch(void* const* d_in, const int* in_sizes, int n_in,
                              void* d_out, int out_size, void* d_ws, size_t ws_size,
                              hipStream_t stream) {
    const float* x         = (const float*)d_in[0];
    const int*   positions = (const int*)d_in[1];
    float*       out       = (float*)d_out;

    const int n4    = out_size / 4;              // 8388608 float4
    const int block = 256;
    const int grid  = n4 / (block * PER_THREAD); // 2048 (exact: n4 % (256*16) == 0)

    RotaryPositionalEncoding_56178172231979_kernel<<<grid, block, 0, stream>>>(
        x, positions, out);
}